// Round 5
// baseline (435.935 us; speedup 1.0000x reference)
//
#include <hip/hip_runtime.h>

#define EPSV 1e-5f

typedef __bf16 bf16x8 __attribute__((ext_vector_type(8)));
typedef float f32x4 __attribute__((ext_vector_type(4)));
typedef unsigned int u32x4 __attribute__((ext_vector_type(4)));
typedef unsigned short u16x4 __attribute__((ext_vector_type(4)));

__device__ __forceinline__ unsigned short f2bf(float f) {
  return __builtin_bit_cast(unsigned short, static_cast<__bf16>(f));
}

constexpr int Himg = 112, Wimg = 112, HWp = Himg * Wimg;  // 12544

// ---------------------------------------------------------------------------
// prep_misc: pack weights into per-lane MFMA A-fragment order + BN scale/shift.
//   wPack[i], i = ((tap*2+ks)*4 + c)*512 + l*8 + j  (bf16)
//   co = c*16+(l&15), ci = ks*32+(l>>4)*8+j
// ---------------------------------------------------------------------------
__global__ __launch_bounds__(256) void prep_misc(
    const float* __restrict__ w1, const float* __restrict__ w2,
    const float* __restrict__ g1, const float* __restrict__ b1,
    const float* __restrict__ m1, const float* __restrict__ v1,
    const float* __restrict__ g2, const float* __restrict__ b2,
    const float* __restrict__ m2, const float* __restrict__ v2,
    unsigned short* __restrict__ wt1, unsigned short* __restrict__ wt2,
    float* __restrict__ prm)
{
  int id = blockIdx.x * 256 + threadIdx.x;
  for (int i = id; i < 9 * 2 * 4 * 512; i += gridDim.x * 256) {
    int j   = i & 7;
    int l   = (i >> 3) & 63;
    int c   = (i >> 9) & 3;
    int ks  = (i >> 11) & 1;
    int tap = i >> 12;
    int co  = c * 16 + (l & 15);
    int ci  = ks * 32 + (l >> 4) * 8 + j;
    int kh  = tap / 3, kw = tap - kh * 3;
    int src = ((co * 64 + ci) * 3 + kh) * 3 + kw;
    wt1[i] = f2bf(w1[src]);
    wt2[i] = f2bf(w2[src]);
  }
  if (id < 64) {
    float s1 = g1[id] * rsqrtf(v1[id] + EPSV);
    prm[id]      = s1;
    prm[64 + id] = b1[id] - m1[id] * s1;
    float s2 = g2[id] * rsqrtf(v2[id] + EPSV);
    prm[128 + id] = s2;
    prm[192 + id] = b2[id] - m2[id] * s2;
  }
}

// ---------------------------------------------------------------------------
// prep_x0: x NCHW f32 -> x0 = BN0(x) as NHWC bf16
// ---------------------------------------------------------------------------
__global__ __launch_bounds__(256) void prep_x0(
    const float* __restrict__ x,
    const float* __restrict__ g0, const float* __restrict__ b0,
    const float* __restrict__ m0, const float* __restrict__ v0,
    unsigned short* __restrict__ x0)
{
  __shared__ float sc[64];
  __shared__ float sh[64];
  __shared__ float tile[64][113];
  const int t = threadIdx.x;
  const int bid = blockIdx.x;          // n*112 + h
  const int n = bid / 112, h = bid - n * 112;
  if (t < 64) {
    float s = g0[t] * rsqrtf(v0[t] + EPSV);
    sc[t] = s;
    sh[t] = b0[t] - m0[t] * s;
  }
  __syncthreads();
  const float* xp = x + (size_t)n * 64 * HWp + h * Wimg;
  for (int i = t; i < 64 * Wimg; i += 256) {
    int c = i / Wimg, w = i - c * Wimg;
    tile[c][w] = xp[(size_t)c * HWp + w] * sc[c] + sh[c];
  }
  __syncthreads();
  unsigned short* op = x0 + (size_t)bid * Wimg * 64;
  for (int i = t * 4; i < Wimg * 64; i += 1024) {
    int w = i >> 6, c = i & 63;
    u16x4 u;
    u[0] = f2bf(tile[c + 0][w]);
    u[1] = f2bf(tile[c + 1][w]);
    u[2] = f2bf(tile[c + 2][w]);
    u[3] = f2bf(tile[c + 3][w]);
    *reinterpret_cast<u16x4*>(op + i) = u;
  }
}

// ---------------------------------------------------------------------------
// conv3x3r<STAGE>: implicit-GEMM 3x3 conv, FULL-W tiles.  (R3 structure)
//   block: 448 thr = 7 waves; tile = 2 rows x 112 w x 64 co
//   wave wv: w-span [wv*16, wv*16+16), both rows, all 64 co
//   LDS: patch [4 rows][114 wpad][64 ci] bf16 = 58368 B, XOR chunk swizzle
//   weights: global, per-lane packed fragments, DEPTH-4 register ring,
//            VMEM issue order pinned with sched_barrier(0x38F) so the
//            allocator cannot sink the prefetch to its use (R3's VGPR=64
//            indicated exactly that sinking).  Zero in-loop barriers.
//   D[co][pixel]: co = c*16 + grp*4 + reg, pixel(w) = wv*16 + lo
// ---------------------------------------------------------------------------
template <int STAGE>
__global__ __launch_bounds__(448, 4) void conv3x3r(
    const unsigned short* __restrict__ src,   // bf16 NHWC [P][64]
    const unsigned short* __restrict__ wP,    // packed bf16 fragments
    const float* __restrict__ scale, const float* __restrict__ shift,
    const float* __restrict__ aP,
    unsigned short* __restrict__ dstb,        // STAGE 1 out
    float* __restrict__ dstf,                 // STAGE 2 out
    const float* __restrict__ resid)          // STAGE 2 residual
{
  __shared__ __align__(16) unsigned char lds[4 * 114 * 128];  // 58368 B
  const int t = threadIdx.x;
  // XCD-chunked bijective swizzle: 3584 = 8 * 448
  const int b = blockIdx.x;
  const int swz = (b & 7) * 448 + (b >> 3);
  const int n = swz / 56, hb = swz - n * 56;
  const int h0 = hb * 2;
  const size_t ibase = (size_t)n * HWp;

  // ---- halo zero: wpad 0 and 113, 4 rows, 8 chunks ----
  if (t < 64) {
    int r = t >> 4, wp = ((t >> 3) & 1) ? 113 : 0, k = t & 7;
    int P = r * 114 + wp;
    u32x4 z = {0u, 0u, 0u, 0u};
    *reinterpret_cast<u32x4*>(&lds[P * 128 + ((k ^ (P & 7)) << 4)]) = z;
  }
  // ---- stage 4 input rows (h0-1 .. h0+2), contiguous row reads ----
  for (int i = t; i < 4 * 112 * 8; i += 448) {   // exactly 8 iters
    int r = i / 896, rem = i - r * 896;
    int w = rem >> 3, k = rem & 7;
    int hh = h0 - 1 + r;
    u32x4 val = {0u, 0u, 0u, 0u};
    if ((unsigned)hh < 112u)
      val = *reinterpret_cast<const u32x4*>(src + (ibase + hh * Wimg + w) * 64 + k * 8);
    int P = r * 114 + w + 1;
    *reinterpret_cast<u32x4*>(&lds[P * 128 + ((k ^ (P & 7)) << 4)]) = val;
  }
  __syncthreads();

  const int wv = t >> 6, l = t & 63;
  const int lo = l & 15, grp = l >> 4;

  f32x4 acc[4][2];
#pragma unroll
  for (int c = 0; c < 4; ++c)
#pragma unroll
    for (int p = 0; p < 2; ++p) {
      f32x4 z = {0.f, 0.f, 0.f, 0.f};
      acc[c][p] = z;
    }

  // weight fragment ring, DEPTH 4: 18 steps = 9 taps x 2 K-halves
  const unsigned short* wl = wP + l * 8;
  bf16x8 wr[4][4];
#pragma unroll
  for (int s0 = 0; s0 < 4; ++s0)
#pragma unroll
    for (int c = 0; c < 4; ++c)
      wr[s0][c] = *reinterpret_cast<const bf16x8*>(wl + (s0 * 4 + c) * 512);
  // pin: the preloads may not sink below this point
  __builtin_amdgcn_sched_barrier(0x38F);

#pragma unroll
  for (int s = 0; s < 18; ++s) {
    const int tap = s >> 1, ks = s & 1;
    const int dh = tap / 3, dw = tap - (tap / 3) * 3;
    bf16x8 pf[2];
#pragma unroll
    for (int p = 0; p < 2; ++p) {
      int P = (p + dh) * 114 + wv * 16 + lo + dw;
      pf[p] = *reinterpret_cast<const bf16x8*>(
          &lds[P * 128 + ((((ks << 2) + grp) ^ (P & 7)) << 4)]);
    }
#pragma unroll
    for (int c = 0; c < 4; ++c)
#pragma unroll
      for (int p = 0; p < 2; ++p)
        acc[c][p] = __builtin_amdgcn_mfma_f32_16x16x32_bf16(wr[s & 3][c], pf[p], acc[c][p], 0, 0, 0);
    // VMEM may not cross; ALU/MFMA/DS may (mask 0x38F = ALL & ~VMEM*)
    __builtin_amdgcn_sched_barrier(0x38F);
    if (s < 14) {
#pragma unroll
      for (int c = 0; c < 4; ++c)
        wr[(s + 4) & 3][c] = *reinterpret_cast<const bf16x8*>(wl + ((s + 4) * 4 + c) * 512);
      __builtin_amdgcn_sched_barrier(0x38F);
    }
  }

  // ---- epilogue ----  D[co][pixel]: co = c*16+grp*4+j, w = wv*16+lo
#pragma unroll
  for (int c = 0; c < 4; ++c) {
    const int co0 = c * 16 + grp * 4;
    float s_[4], h_[4], a_[4];
#pragma unroll
    for (int j = 0; j < 4; ++j) {
      s_[j] = scale[co0 + j];
      h_[j] = shift[co0 + j];
      a_[j] = aP[co0 + j];
    }
    const int w = wv * 16 + lo;
#pragma unroll
    for (int p = 0; p < 2; ++p) {
      const int hh = h0 + p;
      f32x4 v = acc[c][p];
      if (STAGE == 1) {
        u16x4 u;
#pragma unroll
        for (int j = 0; j < 4; ++j) {
          float vv = v[j] * s_[j] + h_[j];
          vv = vv >= 0.f ? vv : vv * a_[j];
          u[j] = f2bf(vv);
        }
        *reinterpret_cast<u16x4*>(dstb + (ibase + hh * Wimg + w) * 64 + co0) = u;
      } else {
#pragma unroll
        for (int j = 0; j < 4; ++j) {
          size_t idx = ((size_t)(n * 64 + co0 + j) * Himg + hh) * Wimg + w;
          float vv = v[j] * s_[j] + h_[j] + resid[idx];
          vv = vv >= 0.f ? vv : vv * a_[j];
          dstf[idx] = vv;
        }
      }
    }
  }
}

// ---------------------------------------------------------------------------
// scratch map:
//   d_out[0 .. 102,760,448)     : x0 bf16 NHWC (dead before conv2 writes)
//   d_ws [0 .. 102,760,448)     : y1 bf16 NHWC
//   d_ws [+0 .. +73,728)        : wt1 packed bf16
//   d_ws [+73,728 .. +147,456)  : wt2 packed bf16
//   d_ws [+147,456 .. +148,480) : prm f32
// ---------------------------------------------------------------------------
extern "C" void kernel_launch(void* const* d_in, const int* in_sizes, int n_in,
                              void* d_out, int out_size, void* d_ws, size_t ws_size,
                              hipStream_t stream)
{
  const float* x  = (const float*)d_in[0];
  const float* w1 = (const float*)d_in[1];
  const float* w2 = (const float*)d_in[2];
  const float* g0 = (const float*)d_in[3];
  const float* b0 = (const float*)d_in[4];
  const float* m0 = (const float*)d_in[5];
  const float* v0 = (const float*)d_in[6];
  const float* g1 = (const float*)d_in[7];
  const float* b1 = (const float*)d_in[8];
  const float* m1 = (const float*)d_in[9];
  const float* v1 = (const float*)d_in[10];
  const float* g2 = (const float*)d_in[11];
  const float* b2 = (const float*)d_in[12];
  const float* m2 = (const float*)d_in[13];
  const float* v2 = (const float*)d_in[14];
  const float* a1 = (const float*)d_in[15];
  const float* a2 = (const float*)d_in[16];

  unsigned short* x0 = (unsigned short*)d_out;
  unsigned char* wsb = (unsigned char*)d_ws;
  unsigned short* y1  = (unsigned short*)wsb;
  unsigned short* wt1 = (unsigned short*)(wsb + 102760448);
  unsigned short* wt2 = (unsigned short*)(wsb + 102760448 + 73728);
  float* prm          = (float*)(wsb + 102760448 + 2 * 73728);

  prep_misc<<<16, 256, 0, stream>>>(w1, w2, g1, b1, m1, v1, g2, b2, m2, v2, wt1, wt2, prm);
  prep_x0<<<64 * 112, 256, 0, stream>>>(x, g0, b0, m0, v0, x0);
  conv3x3r<1><<<3584, 448, 0, stream>>>(x0, wt1, prm, prm + 64, a1, y1, nullptr, nullptr);
  conv3x3r<2><<<3584, 448, 0, stream>>>(y1, wt2, prm + 128, prm + 192, a2, nullptr, (float*)d_out, x);
}

// Round 6
// 286.799 us; speedup vs baseline: 1.5200x; 1.5200x over previous
//
#include <hip/hip_runtime.h>

#define EPSV 1e-5f

typedef __bf16 bf16x8 __attribute__((ext_vector_type(8)));
typedef float f32x4 __attribute__((ext_vector_type(4)));
typedef unsigned int u32x4 __attribute__((ext_vector_type(4)));
typedef unsigned short u16x4 __attribute__((ext_vector_type(4)));

__device__ __forceinline__ unsigned short f2bf(float f) {
  return __builtin_bit_cast(unsigned short, static_cast<__bf16>(f));
}

constexpr int Himg = 112, Wimg = 112, HWp = Himg * Wimg;  // 12544

// ---------------------------------------------------------------------------
// prep_misc: pack weights into per-lane MFMA A-fragment order + BN scale/shift.
//   wPack[i], i = ((tap*2+ks)*4 + c)*512 + l*8 + j  (bf16)
//   co = c*16+(l&15), ci = ks*32+(l>>4)*8+j
// ---------------------------------------------------------------------------
__global__ __launch_bounds__(256) void prep_misc(
    const float* __restrict__ w1, const float* __restrict__ w2,
    const float* __restrict__ g1, const float* __restrict__ b1,
    const float* __restrict__ m1, const float* __restrict__ v1,
    const float* __restrict__ g2, const float* __restrict__ b2,
    const float* __restrict__ m2, const float* __restrict__ v2,
    unsigned short* __restrict__ wt1, unsigned short* __restrict__ wt2,
    float* __restrict__ prm)
{
  int id = blockIdx.x * 256 + threadIdx.x;
  for (int i = id; i < 9 * 2 * 4 * 512; i += gridDim.x * 256) {
    int j   = i & 7;
    int l   = (i >> 3) & 63;
    int c   = (i >> 9) & 3;
    int ks  = (i >> 11) & 1;
    int tap = i >> 12;
    int co  = c * 16 + (l & 15);
    int ci  = ks * 32 + (l >> 4) * 8 + j;
    int kh  = tap / 3, kw = tap - kh * 3;
    int src = ((co * 64 + ci) * 3 + kh) * 3 + kw;
    wt1[i] = f2bf(w1[src]);
    wt2[i] = f2bf(w2[src]);
  }
  if (id < 64) {
    float s1 = g1[id] * rsqrtf(v1[id] + EPSV);
    prm[id]      = s1;
    prm[64 + id] = b1[id] - m1[id] * s1;
    float s2 = g2[id] * rsqrtf(v2[id] + EPSV);
    prm[128 + id] = s2;
    prm[192 + id] = b2[id] - m2[id] * s2;
  }
}

// ---------------------------------------------------------------------------
// prep_x0: x NCHW f32 -> x0 = BN0(x) as NHWC bf16
// ---------------------------------------------------------------------------
__global__ __launch_bounds__(256) void prep_x0(
    const float* __restrict__ x,
    const float* __restrict__ g0, const float* __restrict__ b0,
    const float* __restrict__ m0, const float* __restrict__ v0,
    unsigned short* __restrict__ x0)
{
  __shared__ float sc[64];
  __shared__ float sh[64];
  __shared__ float tile[64][113];
  const int t = threadIdx.x;
  const int bid = blockIdx.x;          // n*112 + h
  const int n = bid / 112, h = bid - n * 112;
  if (t < 64) {
    float s = g0[t] * rsqrtf(v0[t] + EPSV);
    sc[t] = s;
    sh[t] = b0[t] - m0[t] * s;
  }
  __syncthreads();
  const float* xp = x + (size_t)n * 64 * HWp + h * Wimg;
  for (int i = t; i < 64 * Wimg; i += 256) {
    int c = i / Wimg, w = i - c * Wimg;
    tile[c][w] = xp[(size_t)c * HWp + w] * sc[c] + sh[c];
  }
  __syncthreads();
  unsigned short* op = x0 + (size_t)bid * Wimg * 64;
  for (int i = t * 4; i < Wimg * 64; i += 1024) {
    int w = i >> 6, c = i & 63;
    u16x4 u;
    u[0] = f2bf(tile[c + 0][w]);
    u[1] = f2bf(tile[c + 1][w]);
    u[2] = f2bf(tile[c + 2][w]);
    u[3] = f2bf(tile[c + 3][w]);
    *reinterpret_cast<u16x4*>(op + i) = u;
  }
}

// ---------------------------------------------------------------------------
// conv3x3p<STAGE>: grid-persistent implicit-GEMM 3x3 conv.
//   grid 256 blocks (1/CU), 448 thr = 7 waves. Block owns image n=b>>2,
//   rows [q*28, q*28+28) (q=b&3), processed as 7 tiles of 4 rows x 112 w.
//   LDS (161280 B, 1 block/CU):
//     [0 .. 87552)      patch ring: 6 row-slots x [114 P][128 B], XOR chunk swz
//     [87552 .. 161280) weights, full K: [18 step][4 c][1024 B], staged ONCE
//   per tile: T14 prefetch next 4 rows (global->reg) BEFORE K-loop;
//             K-loop = 18 steps x (4 wf + 4 pf ds_read_b128 + 16 MFMA),
//             zero VMEM; epilogue; barrier; ds_write new rows; barrier; rotate.
//   D[co][pixel]: co = c*16+grp*4+reg, w = wv*16+lo
// ---------------------------------------------------------------------------
template <int STAGE>
__global__ __launch_bounds__(448, 2) void conv3x3p(
    const unsigned short* __restrict__ src,   // bf16 NHWC [P][64]
    const unsigned short* __restrict__ wP,    // packed bf16 fragments (73728 B)
    const float* __restrict__ scale, const float* __restrict__ shift,
    const float* __restrict__ aP,
    unsigned short* __restrict__ dstb,        // STAGE 1 out
    float* __restrict__ dstf,                 // STAGE 2 out
    const float* __restrict__ resid)          // STAGE 2 residual
{
  constexpr int RS   = 114 * 128;   // 14592 B per row-slot
  constexpr int WOFF = 6 * RS;      // 87552
  __shared__ __align__(16) unsigned char lds[WOFF + 73728];  // 161280 B

  const int t = threadIdx.x;
  const int b = blockIdx.x;
  const int n = b >> 2, q = b & 3;
  const int qbase = q * 28;
  const size_t ibase = (size_t)n * HWp;

  const int wv = t >> 6, l = t & 63;
  const int lo = l & 15, grp = l >> 4;

  // ---------------- prologue ----------------
  // weights: 4608 x 16B chunks, linear
#pragma unroll
  for (int it = 0; it < 11; ++it) {
    int idx = t + it * 448;
    if (it < 10 || idx < 4608) {
      u32x4 v = *reinterpret_cast<const u32x4*>(wP + idx * 8);
      *reinterpret_cast<u32x4*>(&lds[WOFF + idx * 16]) = v;
    }
  }
  // wpad zero columns (P=0,113) for all 6 slots — written once, never dirtied
  if (t < 96) {
    int r = t >> 4, P = ((t >> 3) & 1) ? 113 : 0, k = t & 7;
    u32x4 z = {0u, 0u, 0u, 0u};
    *reinterpret_cast<u32x4*>(&lds[r * RS + P * 128 + ((k ^ (P & 7)) << 4)]) = z;
  }
  // patch rows qbase-1 .. qbase+4 into slots 0..5
#pragma unroll
  for (int it = 0; it < 12; ++it) {
    int r = it >> 1;                       // compile-time row index
    int rem = t + (it & 1) * 448;
    int w = rem >> 3, k = rem & 7;
    int hh = qbase - 1 + r;
    u32x4 val = {0u, 0u, 0u, 0u};
    if ((unsigned)hh < 112u)
      val = *reinterpret_cast<const u32x4*>(src + (ibase + hh * Wimg + w) * 64 + k * 8);
    int P = w + 1;
    *reinterpret_cast<u32x4*>(&lds[r * RS + P * 128 + ((k ^ (P & 7)) << 4)]) = val;
  }
  __syncthreads();

  int rb0 = 0 * RS, rb1 = 1 * RS, rb2 = 2 * RS, rb3 = 3 * RS, rb4 = 4 * RS, rb5 = 5 * RS;

  for (int T = 0; T < 7; ++T) {
    const int r0 = qbase + T * 4;

    // ---- T14: prefetch next tile's 4 rows (global -> regs) ----
    u32x4 preg[8];
    if (T < 6) {
#pragma unroll
      for (int it = 0; it < 8; ++it) {
        int j = it >> 1;                   // compile-time
        int rem = t + (it & 1) * 448;
        int w = rem >> 3, k = rem & 7;
        int hh = r0 + 5 + j;
        u32x4 val = {0u, 0u, 0u, 0u};
        if (hh < 112)
          val = *reinterpret_cast<const u32x4*>(src + (ibase + hh * Wimg + w) * 64 + k * 8);
        preg[it] = val;
      }
    }

    f32x4 acc[4][4];
#pragma unroll
    for (int c = 0; c < 4; ++c)
#pragma unroll
      for (int p = 0; p < 4; ++p) {
        f32x4 z = {0.f, 0.f, 0.f, 0.f};
        acc[c][p] = z;
      }

    // ---- K-loop: 18 steps, pure LDS + MFMA ----
#pragma unroll
    for (int s = 0; s < 18; ++s) {
      const int tap = s >> 1, ks = s & 1;
      const int dh = tap / 3, dw = tap - dh * 3;
      bf16x8 wf[4], pf[4];
#pragma unroll
      for (int c = 0; c < 4; ++c)
        wf[c] = *reinterpret_cast<const bf16x8*>(&lds[WOFF + (s * 4 + c) * 1024 + l * 16]);
      const int Pr = wv * 16 + lo + dw;
      const int c8 = (ks << 2) | grp;
      const int pbyte = Pr * 128 + ((c8 ^ (Pr & 7)) << 4);
#pragma unroll
      for (int p = 0; p < 4; ++p) {
        const int rr = p + dh;             // compile-time 0..5
        const int rbr = (rr == 0) ? rb0 : (rr == 1) ? rb1 : (rr == 2) ? rb2
                      : (rr == 3) ? rb3 : (rr == 4) ? rb4 : rb5;
        pf[p] = *reinterpret_cast<const bf16x8*>(&lds[rbr + pbyte]);
      }
#pragma unroll
      for (int c = 0; c < 4; ++c)
#pragma unroll
        for (int p = 0; p < 4; ++p)
          acc[c][p] = __builtin_amdgcn_mfma_f32_16x16x32_bf16(wf[c], pf[p], acc[c][p], 0, 0, 0);
    }

    // ---- epilogue: rows r0..r0+3 ----
#pragma unroll
    for (int c = 0; c < 4; ++c) {
      const int co0 = c * 16 + grp * 4;
      float s_[4], h_[4], a_[4];
#pragma unroll
      for (int j = 0; j < 4; ++j) {
        s_[j] = scale[co0 + j];
        h_[j] = shift[co0 + j];
        a_[j] = aP[co0 + j];
      }
      const int w = wv * 16 + lo;
#pragma unroll
      for (int p = 0; p < 4; ++p) {
        const int hh = r0 + p;
        f32x4 v = acc[c][p];
        if (STAGE == 1) {
          u16x4 u;
#pragma unroll
          for (int j = 0; j < 4; ++j) {
            float vv = v[j] * s_[j] + h_[j];
            vv = vv >= 0.f ? vv : vv * a_[j];
            u[j] = f2bf(vv);
          }
          *reinterpret_cast<u16x4*>(dstb + (ibase + hh * Wimg + w) * 64 + co0) = u;
        } else {
#pragma unroll
          for (int j = 0; j < 4; ++j) {
            size_t idx = ((size_t)(n * 64 + co0 + j) * Himg + hh) * Wimg + w;
            float vv = v[j] * s_[j] + h_[j] + resid[idx];
            vv = vv >= 0.f ? vv : vv * a_[j];
            dstf[idx] = vv;
          }
        }
      }
    }

    __syncthreads();   // all waves done reading slots about to be overwritten
    if (T < 6) {
#pragma unroll
      for (int it = 0; it < 8; ++it) {
        int j = it >> 1;                   // compile-time
        int rem = t + (it & 1) * 448;
        int w = rem >> 3, k = rem & 7;
        int P = w + 1;
        const int dst = (j == 0) ? rb0 : (j == 1) ? rb1 : (j == 2) ? rb2 : rb3;
        *reinterpret_cast<u32x4*>(&lds[dst + P * 128 + ((k ^ (P & 7)) << 4)]) = preg[it];
      }
      __syncthreads();
    }
    // rotate ring by 4 rows: new(0..5) = old(4,5,0,1,2,3)
    int n0 = rb4, n1 = rb5, n2 = rb0, n3 = rb1, n4 = rb2, n5 = rb3;
    rb0 = n0; rb1 = n1; rb2 = n2; rb3 = n3; rb4 = n4; rb5 = n5;
  }
}

// ---------------------------------------------------------------------------
// scratch map:
//   d_out[0 .. 102,760,448)     : x0 bf16 NHWC (dead before conv2 writes)
//   d_ws [0 .. 102,760,448)     : y1 bf16 NHWC
//   d_ws [+0 .. +73,728)        : wt1 packed bf16
//   d_ws [+73,728 .. +147,456)  : wt2 packed bf16
//   d_ws [+147,456 .. +148,480) : prm f32
// ---------------------------------------------------------------------------
extern "C" void kernel_launch(void* const* d_in, const int* in_sizes, int n_in,
                              void* d_out, int out_size, void* d_ws, size_t ws_size,
                              hipStream_t stream)
{
  const float* x  = (const float*)d_in[0];
  const float* w1 = (const float*)d_in[1];
  const float* w2 = (const float*)d_in[2];
  const float* g0 = (const float*)d_in[3];
  const float* b0 = (const float*)d_in[4];
  const float* m0 = (const float*)d_in[5];
  const float* v0 = (const float*)d_in[6];
  const float* g1 = (const float*)d_in[7];
  const float* b1 = (const float*)d_in[8];
  const float* m1 = (const float*)d_in[9];
  const float* v1 = (const float*)d_in[10];
  const float* g2 = (const float*)d_in[11];
  const float* b2 = (const float*)d_in[12];
  const float* m2 = (const float*)d_in[13];
  const float* v2 = (const float*)d_in[14];
  const float* a1 = (const float*)d_in[15];
  const float* a2 = (const float*)d_in[16];

  unsigned short* x0 = (unsigned short*)d_out;
  unsigned char* wsb = (unsigned char*)d_ws;
  unsigned short* y1  = (unsigned short*)wsb;
  unsigned short* wt1 = (unsigned short*)(wsb + 102760448);
  unsigned short* wt2 = (unsigned short*)(wsb + 102760448 + 73728);
  float* prm          = (float*)(wsb + 102760448 + 2 * 73728);

  prep_misc<<<16, 256, 0, stream>>>(w1, w2, g1, b1, m1, v1, g2, b2, m2, v2, wt1, wt2, prm);
  prep_x0<<<64 * 112, 256, 0, stream>>>(x, g0, b0, m0, v0, x0);
  conv3x3p<1><<<256, 448, 0, stream>>>(x0, wt1, prm, prm + 64, a1, y1, nullptr, nullptr);
  conv3x3p<2><<<256, 448, 0, stream>>>(y1, wt2, prm + 128, prm + 192, a2, nullptr, (float*)d_out, x);
}